// Round 4
// baseline (13877.328 us; speedup 1.0000x reference)
//
#include <hip/hip_runtime.h>
#include <hip/hip_bf16.h>

#define B_ 2
#define S_ 1024
#define D_ 768
#define H_ 12
#define DH_ 64
#define L_ 6
#define F_ 3072
#define R_ 32

static __device__ __forceinline__ float b2f(__hip_bfloat16 x) { return __bfloat162float(x); }

// ---------------- embedding -> x (f32, lives in d_out) ----------------
__global__ __launch_bounds__(256) void embed_kernel(
    const int* __restrict__ tok, const int* __restrict__ seg,
    const int* __restrict__ pos, const int* __restrict__ qm,
    const float* __restrict__ tok_emb, const float* __restrict__ seg_emb,
    float* __restrict__ x) {
  int row = blockIdx.x;              // b*S + s
  int t = tok[row], sg = seg[row], q = qm[row];
  int p = pos[row] * q;
  float fq = (float)q;
  for (int d = threadIdx.x; d < D_; d += 256) {
    float val = tok_emb[(size_t)t * D_ + d] + seg_emb[(size_t)sg * D_ + d];
    float e = (float)(2 * (d / 2)) / (float)D_;
    float ang = (float)p / powf(10000.0f, e);
    float pt = ((d & 1) == 0) ? sinf(ang) : cosf(ang);
    x[(size_t)row * D_ + d] = val + pt * fq;
  }
}

// ---------------- layernorm; output f32 or bf16 (outBf) ----------------
__global__ __launch_bounds__(256) void ln_kernel(
    const float* __restrict__ X, const float* __restrict__ g,
    const float* __restrict__ bta, void* __restrict__ Y, int outBf) {
  __shared__ float red[256];
  int row = blockIdx.x;
  int tid = threadIdx.x;
  const float* xr = X + (size_t)row * D_;
  float x0 = xr[tid], x1 = xr[tid + 256], x2 = xr[tid + 512];
  red[tid] = x0 + x1 + x2;
  __syncthreads();
  for (int s = 128; s > 0; s >>= 1) { if (tid < s) red[tid] += red[tid + s]; __syncthreads(); }
  float mu = red[0] * (1.0f / 768.0f);
  __syncthreads();
  float d0 = x0 - mu, d1 = x1 - mu, d2 = x2 - mu;
  red[tid] = d0 * d0 + d1 * d1 + d2 * d2;
  __syncthreads();
  for (int s = 128; s > 0; s >>= 1) { if (tid < s) red[tid] += red[tid + s]; __syncthreads(); }
  float var = red[0] * (1.0f / 768.0f);
  float rs = rsqrtf(var + 1e-12f);
  float y0 = d0 * rs * g[tid]       + bta[tid];
  float y1 = d1 * rs * g[tid + 256] + bta[tid + 256];
  float y2 = d2 * rs * g[tid + 512] + bta[tid + 512];
  size_t base = (size_t)row * D_;
  if (outBf) {
    __hip_bfloat16* yr = (__hip_bfloat16*)Y;
    yr[base + tid]       = __float2bfloat16(y0);
    yr[base + tid + 256] = __float2bfloat16(y1);
    yr[base + tid + 512] = __float2bfloat16(y2);
  } else {
    float* yr = (float*)Y;
    yr[base + tid] = y0; yr[base + tid + 256] = y1; yr[base + tid + 512] = y2;
  }
}

// ---------------- generic GEMM: C = op(A[M,K] @ W[K,N] + bias) ----------------
// flags: bit0 = residual add into f32 C, bit1 = gelu(tanh), bit2 = A is bf16,
//        bit3 = C is bf16 (plain store)
__global__ __launch_bounds__(256) void gemm_kernel(
    const void* __restrict__ A, const float* __restrict__ W,
    const float* __restrict__ bias, void* __restrict__ C,
    int M, int N, int K, int flags) {
  const int aBf = flags & 4;
  __shared__ float As[16 * 65];
  __shared__ float Ws[16 * 65];
  int t = threadIdx.x;
  int tx = t & 15, ty = t >> 4;
  int n0 = blockIdx.x * 64, m0 = blockIdx.y * 64;
  float acc[4][4] = {};
  for (int k0 = 0; k0 < K; k0 += 16) {
#pragma unroll
    for (int p = 0; p < 4; ++p) {
      int m = p * 16 + ty;
      size_t idx = (size_t)(m0 + m) * K + (k0 + tx);
      As[tx * 65 + m] = aBf ? b2f(((const __hip_bfloat16*)A)[idx]) : ((const float*)A)[idx];
    }
#pragma unroll
    for (int p = 0; p < 4; ++p) {
      int kk = p * 4 + (t >> 6);
      int n = t & 63;
      Ws[kk * 65 + n] = W[(size_t)(k0 + kk) * N + (n0 + n)];
    }
    __syncthreads();
#pragma unroll
    for (int kk = 0; kk < 16; ++kk) {
      float a[4], bb[4];
#pragma unroll
      for (int i = 0; i < 4; ++i) a[i] = As[kk * 65 + ty * 4 + i];
#pragma unroll
      for (int j = 0; j < 4; ++j) bb[j] = Ws[kk * 65 + tx * 4 + j];
#pragma unroll
      for (int i = 0; i < 4; ++i)
#pragma unroll
        for (int j = 0; j < 4; ++j)
          acc[i][j] += a[i] * bb[j];
    }
    __syncthreads();
  }
#pragma unroll
  for (int i = 0; i < 4; ++i) {
    int m = m0 + ty * 4 + i;
#pragma unroll
    for (int j = 0; j < 4; ++j) {
      int n = n0 + tx * 4 + j;
      float val = acc[i][j] + bias[n];
      if (flags & 2) {
        float u = val;
        float c = 0.7978845608028654f * (u + 0.044715f * u * u * u);
        val = 0.5f * u * (1.0f + tanhf(c));
      }
      size_t idx = (size_t)m * N + n;
      if (flags & 8) {
        ((__hip_bfloat16*)C)[idx] = __float2bfloat16(val);
      } else {
        float* Cf = (float*)C;
        if (flags & 1) Cf[idx] += val; else Cf[idx] = val;
      }
    }
  }
}

// ---------------- fused attention: one block per (b,h,i) query row ----------------
// qkvBf: q,k,v buffers are bf16; outBf: ctx store dtype (must match h dtype)
__global__ __launch_bounds__(256) void attn_kernel(
    const void* __restrict__ q, const void* __restrict__ k, const void* __restrict__ v,
    const float* __restrict__ rel_emb,            // [R,H,DH] for this layer
    const int* __restrict__ rel_ids,              // [B,S,S]
    const int* __restrict__ att_mask,             // [B,S,S]
    void* __restrict__ ctx, int qkvBf, int outBf) {
  __shared__ __align__(16) float qs[64];
  __shared__ float relb[32];
  __shared__ float sc[S_];
  __shared__ float red[256];
  __shared__ float cpart[4][64];
  int i = blockIdx.x, h = blockIdx.y, b = blockIdx.z;
  int tid = threadIdx.x;
  const size_t qoff = ((size_t)(b * S_ + i)) * D_ + h * DH_;
  if (tid < 64) {
    qs[tid] = qkvBf ? b2f(((const __hip_bfloat16*)q)[qoff + tid])
                    : ((const float*)q)[qoff + tid];
  }
  __syncthreads();
  if (tid < 32) {
    float acc = 0.0f;
    const float* re = rel_emb + ((size_t)tid * H_ + h) * DH_;
#pragma unroll 8
    for (int d = 0; d < 64; ++d) acc += qs[d] * re[d];
    relb[tid] = acc;
  }
  __syncthreads();
  const size_t kb = (size_t)b * S_ * D_ + h * DH_;
  const int* ridrow = rel_ids + ((size_t)(b * S_ + i)) * S_;
  const int* amrow = att_mask + ((size_t)(b * S_ + i)) * S_;
  for (int j = tid; j < S_; j += 256) {
    float dot = 0.0f;
    if (qkvBf) {
      const __hip_bfloat16* kr = (const __hip_bfloat16*)k + kb + (size_t)j * D_;
#pragma unroll 8
      for (int d = 0; d < 64; ++d) dot += qs[d] * b2f(kr[d]);
    } else {
      const float4* kr = (const float4*)((const float*)k + kb + (size_t)j * D_);
      const float4* q4 = (const float4*)qs;
#pragma unroll
      for (int d4 = 0; d4 < 16; ++d4) {
        float4 kk4 = kr[d4]; float4 qq4 = q4[d4];
        dot += kk4.x * qq4.x + kk4.y * qq4.y + kk4.z * qq4.z + kk4.w * qq4.w;
      }
    }
    float biasv = (1.0f - (float)amrow[j]) * -10000.0f;
    sc[j] = (dot + relb[ridrow[j]]) * 0.125f + biasv;
  }
  __syncthreads();
  float lm = -3.4e38f;
  for (int j = tid; j < S_; j += 256) lm = fmaxf(lm, sc[j]);
  red[tid] = lm; __syncthreads();
  for (int s = 128; s > 0; s >>= 1) { if (tid < s) red[tid] = fmaxf(red[tid], red[tid + s]); __syncthreads(); }
  float mx = red[0];
  __syncthreads();
  float ls = 0.0f;
  for (int j = tid; j < S_; j += 256) { float e = __expf(sc[j] - mx); sc[j] = e; ls += e; }
  red[tid] = ls; __syncthreads();
  for (int s = 128; s > 0; s >>= 1) { if (tid < s) red[tid] += red[tid + s]; __syncthreads(); }
  float inv = 1.0f / red[0];
  int c = tid >> 6, d = tid & 63;
  float acc = 0.0f;
  if (qkvBf) {
    const __hip_bfloat16* vb = (const __hip_bfloat16*)v + (size_t)b * S_ * D_ + h * DH_ + d;
    for (int j = c * 256; j < c * 256 + 256; ++j) acc += sc[j] * b2f(vb[(size_t)j * D_]);
  } else {
    const float* vb = (const float*)v + (size_t)b * S_ * D_ + h * DH_ + d;
    for (int j = c * 256; j < c * 256 + 256; ++j) acc += sc[j] * vb[(size_t)j * D_];
  }
  cpart[c][d] = acc;
  __syncthreads();
  if (tid < 64) {
    float r = (cpart[0][tid] + cpart[1][tid] + cpart[2][tid] + cpart[3][tid]) * inv;
    size_t o = ((size_t)(b * S_ + i)) * D_ + h * DH_ + tid;
    if (outBf) ((__hip_bfloat16*)ctx)[o] = __float2bfloat16(r);
    else ((float*)ctx)[o] = r;
  }
}

extern "C" void kernel_launch(void* const* d_in, const int* in_sizes, int n_in,
                              void* d_out, int out_size, void* d_ws, size_t ws_size,
                              hipStream_t stream) {
  const int* token_ids    = (const int*)d_in[0];
  const int* segment_ids  = (const int*)d_in[1];
  const int* position_ids = (const int*)d_in[2];
  const int* question_mask= (const int*)d_in[3];
  const int* att_mask     = (const int*)d_in[4];
  const int* rel_ids      = (const int*)d_in[5];
  const float* tok_emb = (const float*)d_in[6];
  const float* seg_emb = (const float*)d_in[7];
  const float* ln1_g = (const float*)d_in[8];
  const float* ln1_b = (const float*)d_in[9];
  const float* ln2_g = (const float*)d_in[10];
  const float* ln2_b = (const float*)d_in[11];
  const float* wq = (const float*)d_in[12];
  const float* bq = (const float*)d_in[13];
  const float* wk = (const float*)d_in[14];
  const float* bk = (const float*)d_in[15];
  const float* wv = (const float*)d_in[16];
  const float* bv = (const float*)d_in[17];
  const float* wo = (const float*)d_in[18];
  const float* bo = (const float*)d_in[19];
  const float* rel_emb = (const float*)d_in[20];
  const float* w1 = (const float*)d_in[21];
  const float* b1 = (const float*)d_in[22];
  const float* w2 = (const float*)d_in[23];
  const float* b2 = (const float*)d_in[24];

  const size_t NTOK = (size_t)B_ * S_ * D_;     // 1,572,864 elems
  const size_t F32  = NTOK * 4;                 // 6,291,456 B per f32 activation
  const size_t BF16 = NTOK * 2;                 // 3,145,728 B per bf16 activation

  // x lives in d_out (f32, exactly NTOK elems)
  float* x = (float*)d_out;
  char* ws = (char*)d_ws;

  // Tier on ws_size (constant across launches -> graph-safe):
  //  T2 (>= 25.2MB): h,q,k,v f32; ffn bf16 aliased over q+k (12.58MB)
  //  T4 (else, needs 15.7MB): h,q,k,v bf16; ffn bf16 over q..v+3.1MB
  const bool t2 = ws_size >= (4 * F32);
  void *h, *q, *k, *v, *ffn;
  int actBf;          // h/q/k/v dtype: 0=f32, 1=bf16
  if (t2) {
    h = ws; q = ws + F32; k = ws + 2 * F32; v = ws + 3 * F32;
    ffn = ws + F32;                 // over q+k, bf16, needs 2*F32? no: B*S*F bf16 = 12.58MB = 2*F32? (F=4D -> ffn bf16 = 2*NTOK*4 B = 12.58MB) fits q+k (12.58MB)
    actBf = 0;
  } else {
    h = ws; q = ws + BF16; k = ws + 2 * BF16; v = ws + 3 * BF16;
    ffn = ws + BF16;                // bf16 ffn 12.58MB over q,k,v + 3.1MB beyond (total 15.7MB)
    actBf = 1;
  }

  embed_kernel<<<B_ * S_, 256, 0, stream>>>(token_ids, segment_ids, position_ids,
                                            question_mask, tok_emb, seg_emb, x);

  dim3 gProj(D_ / 64, (B_ * S_) / 64);   // (12, 32)
  dim3 gFfn1(F_ / 64, (B_ * S_) / 64);   // (48, 32)
  dim3 gAttn(S_, H_, B_);

  const int aFlag = actBf ? 4 : 0;       // gemm A dtype flag for h-fed gemms
  const int cQkv  = actBf ? 8 : 0;       // q/k/v store dtype

  for (int l = 0; l < L_; ++l) {
    const float* wq_l = wq + (size_t)l * D_ * D_;
    const float* wk_l = wk + (size_t)l * D_ * D_;
    const float* wv_l = wv + (size_t)l * D_ * D_;
    const float* wo_l = wo + (size_t)l * D_ * D_;
    const float* w1_l = w1 + (size_t)l * D_ * F_;
    const float* w2_l = w2 + (size_t)l * F_ * D_;
    const float* re_l = rel_emb + (size_t)l * R_ * H_ * DH_;

    ln_kernel<<<B_ * S_, 256, 0, stream>>>(x, ln1_g + (size_t)l * D_, ln1_b + (size_t)l * D_, h, actBf);
    gemm_kernel<<<gProj, 256, 0, stream>>>(h, wq_l, bq + (size_t)l * D_, q, B_ * S_, D_, D_, aFlag | cQkv);
    gemm_kernel<<<gProj, 256, 0, stream>>>(h, wk_l, bk + (size_t)l * D_, k, B_ * S_, D_, D_, aFlag | cQkv);
    gemm_kernel<<<gProj, 256, 0, stream>>>(h, wv_l, bv + (size_t)l * D_, v, B_ * S_, D_, D_, aFlag | cQkv);
    attn_kernel<<<gAttn, 256, 0, stream>>>(q, k, v, re_l, rel_ids, att_mask, h, actBf, actBf);
    gemm_kernel<<<gProj, 256, 0, stream>>>(h, wo_l, bo + (size_t)l * D_, x, B_ * S_, D_, D_, 1 | aFlag);
    ln_kernel<<<B_ * S_, 256, 0, stream>>>(x, ln2_g + (size_t)l * D_, ln2_b + (size_t)l * D_, h, actBf);
    // FFN1: h @ w1 + b1 -> gelu -> bf16 ffn   (flags: gelu | bf16C | maybe bf16A)
    gemm_kernel<<<gFfn1, 256, 0, stream>>>(h, w1_l, b1 + (size_t)l * F_, ffn, B_ * S_, F_, D_, 2 | 8 | aFlag);
    // FFN2: ffn(bf16) @ w2 + b2 += x          (flags: residual | bf16A)
    gemm_kernel<<<gProj, 256, 0, stream>>>(ffn, w2_l, b2 + (size_t)l * D_, x, B_ * S_, D_, F_, 1 | 4);
  }
  // x == d_out (f32): no final cast needed.
}

// Round 5
// 3589.960 us; speedup vs baseline: 3.8656x; 3.8656x over previous
//
#include <hip/hip_runtime.h>
#include <hip/hip_bf16.h>

#define B_ 2
#define S_ 1024
#define D_ 768
#define H_ 12
#define DH_ 64
#define L_ 6
#define F_ 3072
#define R_ 32

typedef __attribute__((ext_vector_type(8))) short short8;
typedef __attribute__((ext_vector_type(4))) float floatx4;

static __device__ __forceinline__ float b2f(__hip_bfloat16 x) { return __bfloat162float(x); }
static __device__ __forceinline__ unsigned short f2bu(float x) {
  __hip_bfloat16 h = __float2bfloat16(x);
  return *(unsigned short*)&h;
}

// ---------------- embedding -> x (f32, lives in d_out) ----------------
__global__ __launch_bounds__(256) void embed_kernel(
    const int* __restrict__ tok, const int* __restrict__ seg,
    const int* __restrict__ pos, const int* __restrict__ qm,
    const float* __restrict__ tok_emb, const float* __restrict__ seg_emb,
    float* __restrict__ x) {
  int row = blockIdx.x;              // b*S + s
  int t = tok[row], sg = seg[row], q = qm[row];
  int p = pos[row] * q;
  float fq = (float)q;
  for (int d = threadIdx.x; d < D_; d += 256) {
    float val = tok_emb[(size_t)t * D_ + d] + seg_emb[(size_t)sg * D_ + d];
    float e = (float)(2 * (d / 2)) / (float)D_;
    float ang = (float)p / powf(10000.0f, e);
    float pt = ((d & 1) == 0) ? sinf(ang) : cosf(ang);
    x[(size_t)row * D_ + d] = val + pt * fq;
  }
}

// ---------------- layernorm: x f32 -> y bf16 ----------------
__global__ __launch_bounds__(256) void ln_kernel(
    const float* __restrict__ X, const float* __restrict__ g,
    const float* __restrict__ bta, __hip_bfloat16* __restrict__ Y) {
  __shared__ float red[256];
  int row = blockIdx.x;
  int tid = threadIdx.x;
  const float* xr = X + (size_t)row * D_;
  float x0 = xr[tid], x1 = xr[tid + 256], x2 = xr[tid + 512];
  red[tid] = x0 + x1 + x2;
  __syncthreads();
  for (int s = 128; s > 0; s >>= 1) { if (tid < s) red[tid] += red[tid + s]; __syncthreads(); }
  float mu = red[0] * (1.0f / 768.0f);
  __syncthreads();
  float d0 = x0 - mu, d1 = x1 - mu, d2 = x2 - mu;
  red[tid] = d0 * d0 + d1 * d1 + d2 * d2;
  __syncthreads();
  for (int s = 128; s > 0; s >>= 1) { if (tid < s) red[tid] += red[tid + s]; __syncthreads(); }
  float var = red[0] * (1.0f / 768.0f);
  float rs = rsqrtf(var + 1e-12f);
  size_t base = (size_t)row * D_;
  Y[base + tid]       = __float2bfloat16(d0 * rs * g[tid]       + bta[tid]);
  Y[base + tid + 256] = __float2bfloat16(d1 * rs * g[tid + 256] + bta[tid + 256]);
  Y[base + tid + 512] = __float2bfloat16(d2 * rs * g[tid + 512] + bta[tid + 512]);
}

// ---------------- MFMA GEMM: C[M,N] = op(A[M,K](bf16) @ W[K,N](f32->bf16) + bias) ----------------
// flags: bit0 = residual add into f32 C, bit1 = gelu(tanh), bit3 = C bf16 store
#define GF_RES 1
#define GF_GELU 2
#define GF_BF16OUT 8

__global__ __launch_bounds__(256) void gemm_mfma(
    const __hip_bfloat16* __restrict__ A, const float* __restrict__ W,
    const float* __restrict__ bias, void* __restrict__ C,
    int M, int N, int K, int flags) {
  // LDS layout: [kquad 0..3][row 0..127][elem 0..7] -> conflict-free b128 frag reads
  __shared__ short sA[4 * 128 * 8];
  __shared__ short sB[4 * 128 * 8];
  int t = threadIdx.x;
  int w = t >> 6, lane = t & 63;
  int wm = w >> 1, wn = w & 1;
  int q4 = lane >> 4, l16 = lane & 15;
  int m0 = blockIdx.y * 128, n0 = blockIdx.x * 128;

  floatx4 acc[4][4] = {};

  int arow = t >> 1, ahalf = t & 1;       // A staging: 128 rows x 32 k
  int wk = t >> 3, ng = (t & 7) * 16;     // W staging: 32 k x 128 n

  for (int k0 = 0; k0 < K; k0 += 32) {
    // stage A: 16 bf16 per thread (two 16B chunks = kquads ahalf*2, ahalf*2+1)
    const uint4* ga = (const uint4*)(A + (size_t)(m0 + arow) * K + k0 + ahalf * 16);
    uint4 a0 = ga[0];
    uint4 a1 = ga[1];
    *(uint4*)&sA[((ahalf * 2 + 0) * 128 + arow) * 8] = a0;
    *(uint4*)&sA[((ahalf * 2 + 1) * 128 + arow) * 8] = a1;
    // stage W: 16 f32 per thread, convert to bf16, transposed store
    const float* gw = W + (size_t)(k0 + wk) * N + n0 + ng;
    int qq = wk >> 3, ki = wk & 7;
#pragma unroll
    for (int e = 0; e < 16; ++e) {
      sB[((qq * 128 + ng + e)) * 8 + ki] = (short)f2bu(gw[e]);
    }
    __syncthreads();
    short8 af[4], bf[4];
#pragma unroll
    for (int mt = 0; mt < 4; ++mt)
      af[mt] = *(short8*)&sA[(q4 * 128 + wm * 64 + mt * 16 + l16) * 8];
#pragma unroll
    for (int nt = 0; nt < 4; ++nt)
      bf[nt] = *(short8*)&sB[(q4 * 128 + wn * 64 + nt * 16 + l16) * 8];
#pragma unroll
    for (int mt = 0; mt < 4; ++mt)
#pragma unroll
      for (int nt = 0; nt < 4; ++nt)
        acc[mt][nt] = __builtin_amdgcn_mfma_f32_16x16x32_bf16(af[mt], bf[nt], acc[mt][nt], 0, 0, 0);
    __syncthreads();
  }

#pragma unroll
  for (int mt = 0; mt < 4; ++mt) {
#pragma unroll
    for (int nt = 0; nt < 4; ++nt) {
      int col = n0 + wn * 64 + nt * 16 + l16;
      float bv = bias[col];
#pragma unroll
      for (int r = 0; r < 4; ++r) {
        int row = m0 + wm * 64 + mt * 16 + q4 * 4 + r;
        float val = acc[mt][nt][r] + bv;
        if (flags & GF_GELU) {
          float u = val;
          float c = 0.7978845608028654f * (u + 0.044715f * u * u * u);
          val = 0.5f * u * (1.0f + tanhf(c));
        }
        size_t idx = (size_t)row * N + col;
        if (flags & GF_BF16OUT) {
          ((__hip_bfloat16*)C)[idx] = __float2bfloat16(val);
        } else if (flags & GF_RES) {
          ((float*)C)[idx] += val;
        } else {
          ((float*)C)[idx] = val;
        }
      }
    }
  }
}

// ---------------- flash-tile attention: block = (64 queries, h, b) ----------------
__global__ __launch_bounds__(256) void attn_fa(
    const __hip_bfloat16* __restrict__ q, const __hip_bfloat16* __restrict__ k,
    const __hip_bfloat16* __restrict__ v, const float* __restrict__ rel_emb,
    const int* __restrict__ rel_ids, const int* __restrict__ att_mask,
    __hip_bfloat16* __restrict__ ctx) {
  __shared__ float Qs[64][68];
  __shared__ float KVs[64][68];
  __shared__ float Ss[64][68];
  __shared__ float relb[64][32];
  int t = threadIdx.x;
  int i0 = blockIdx.x * 64, h = blockIdx.y, b = blockIdx.z;
  int ty = t >> 4, tx = t & 15;
  int lrow = t >> 2, ldq = (t & 3) * 16;   // tile-load mapping: 64 rows x 64 dims

  // load Q tile (bf16 -> f32 LDS)
  {
    const __hip_bfloat16* src = q + ((size_t)(b * S_ + i0 + lrow)) * D_ + h * DH_ + ldq;
    uint4 u0 = *(const uint4*)(src);
    uint4 u1 = *(const uint4*)(src + 8);
    const __hip_bfloat16* p0 = (const __hip_bfloat16*)&u0;
    const __hip_bfloat16* p1 = (const __hip_bfloat16*)&u1;
#pragma unroll
    for (int e = 0; e < 8; ++e) Qs[lrow][ldq + e] = b2f(p0[e]);
#pragma unroll
    for (int e = 0; e < 8; ++e) Qs[lrow][ldq + 8 + e] = b2f(p1[e]);
  }
  __syncthreads();

  // rel bias table: relb[i][r] = Q[i] . rel_emb[r][h]
  {
    int i = t >> 2, rb = (t & 3) * 8;
#pragma unroll
    for (int rr = 0; rr < 8; ++rr) {
      int r = rb + rr;
      const float* re = rel_emb + ((size_t)r * H_ + h) * DH_;
      float acc = 0.0f;
#pragma unroll 8
      for (int d = 0; d < 64; ++d) acc += Qs[i][d] * re[d];
      relb[i][r] = acc;
    }
  }
  __syncthreads();

  float m_old[4] = {-1e30f, -1e30f, -1e30f, -1e30f};
  float lsum[4] = {0.0f, 0.0f, 0.0f, 0.0f};
  float4 O[4];
#pragma unroll
  for (int ii = 0; ii < 4; ++ii) O[ii] = make_float4(0.f, 0.f, 0.f, 0.f);

  for (int jt = 0; jt < S_ / 64; ++jt) {
    int j0 = jt * 64;
    // load K tile
    {
      const __hip_bfloat16* src = k + ((size_t)(b * S_ + j0 + lrow)) * D_ + h * DH_ + ldq;
      uint4 u0 = *(const uint4*)(src);
      uint4 u1 = *(const uint4*)(src + 8);
      const __hip_bfloat16* p0 = (const __hip_bfloat16*)&u0;
      const __hip_bfloat16* p1 = (const __hip_bfloat16*)&u1;
#pragma unroll
      for (int e = 0; e < 8; ++e) KVs[lrow][ldq + e] = b2f(p0[e]);
#pragma unroll
      for (int e = 0; e < 8; ++e) KVs[lrow][ldq + 8 + e] = b2f(p1[e]);
    }
    __syncthreads();

    // scores: 4x4 per thread
    float s[4][4] = {};
    for (int d4 = 0; d4 < 64; d4 += 4) {
      float4 qv[4], kv[4];
#pragma unroll
      for (int ii = 0; ii < 4; ++ii) qv[ii] = *(float4*)&Qs[ty * 4 + ii][d4];
#pragma unroll
      for (int jj = 0; jj < 4; ++jj) kv[jj] = *(float4*)&KVs[tx * 4 + jj][d4];
#pragma unroll
      for (int ii = 0; ii < 4; ++ii)
#pragma unroll
        for (int jj = 0; jj < 4; ++jj)
          s[ii][jj] += qv[ii].x * kv[jj].x + qv[ii].y * kv[jj].y +
                       qv[ii].z * kv[jj].z + qv[ii].w * kv[jj].w;
    }

    // rel bias + mask + scale + online softmax
#pragma unroll
    for (int ii = 0; ii < 4; ++ii) {
      int gi = i0 + ty * 4 + ii;
      const int* rid = rel_ids + ((size_t)(b * S_ + gi)) * S_ + j0 + tx * 4;
      const int* am  = att_mask + ((size_t)(b * S_ + gi)) * S_ + j0 + tx * 4;
      float tmax = -1e30f;
      float sv[4];
#pragma unroll
      for (int jj = 0; jj < 4; ++jj) {
        float sc = (s[ii][jj] + relb[ty * 4 + ii][rid[jj]]) * 0.125f
                   + (1.0f - (float)am[jj]) * -10000.0f;
        sv[jj] = sc;
        tmax = fmaxf(tmax, sc);
      }
#pragma unroll
      for (int off = 1; off < 16; off <<= 1) tmax = fmaxf(tmax, __shfl_xor(tmax, off));
      float mn = fmaxf(m_old[ii], tmax);
      float alpha = __expf(m_old[ii] - mn);
      float ps = 0.0f;
#pragma unroll
      for (int jj = 0; jj < 4; ++jj) {
        float p = __expf(sv[jj] - mn);
        Ss[ty * 4 + ii][tx * 4 + jj] = p;
        ps += p;
      }
#pragma unroll
      for (int off = 1; off < 16; off <<= 1) ps += __shfl_xor(ps, off);
      lsum[ii] = lsum[ii] * alpha + ps;
      m_old[ii] = mn;
      O[ii].x *= alpha; O[ii].y *= alpha; O[ii].z *= alpha; O[ii].w *= alpha;
    }
    __syncthreads();   // Ss complete; K reads done

    // load V tile (overwrites K buffer)
    {
      const __hip_bfloat16* src = v + ((size_t)(b * S_ + j0 + lrow)) * D_ + h * DH_ + ldq;
      uint4 u0 = *(const uint4*)(src);
      uint4 u1 = *(const uint4*)(src + 8);
      const __hip_bfloat16* p0 = (const __hip_bfloat16*)&u0;
      const __hip_bfloat16* p1 = (const __hip_bfloat16*)&u1;
#pragma unroll
      for (int e = 0; e < 8; ++e) KVs[lrow][ldq + e] = b2f(p0[e]);
#pragma unroll
      for (int e = 0; e < 8; ++e) KVs[lrow][ldq + 8 + e] = b2f(p1[e]);
    }
    __syncthreads();

    // PV: O[i][d] += sum_j P[i][j] * V[j][d]
    for (int j = 0; j < 64; ++j) {
      float4 vv = *(float4*)&KVs[j][tx * 4];
#pragma unroll
      for (int ii = 0; ii < 4; ++ii) {
        float pv = Ss[ty * 4 + ii][j];
        O[ii].x += pv * vv.x; O[ii].y += pv * vv.y;
        O[ii].z += pv * vv.z; O[ii].w += pv * vv.w;
      }
    }
    __syncthreads();   // before next K overwrite / Ss rewrite
  }

  // normalize + store ctx (bf16)
#pragma unroll
  for (int ii = 0; ii < 4; ++ii) {
    float inv = 1.0f / lsum[ii];
    int gi = i0 + ty * 4 + ii;
    __hip_bfloat16* dst = ctx + ((size_t)(b * S_ + gi)) * D_ + h * DH_ + tx * 4;
    ushort4 pk;
    pk.x = f2bu(O[ii].x * inv);
    pk.y = f2bu(O[ii].y * inv);
    pk.z = f2bu(O[ii].z * inv);
    pk.w = f2bu(O[ii].w * inv);
    *(ushort4*)dst = pk;
  }
}

extern "C" void kernel_launch(void* const* d_in, const int* in_sizes, int n_in,
                              void* d_out, int out_size, void* d_ws, size_t ws_size,
                              hipStream_t stream) {
  const int* token_ids    = (const int*)d_in[0];
  const int* segment_ids  = (const int*)d_in[1];
  const int* position_ids = (const int*)d_in[2];
  const int* question_mask= (const int*)d_in[3];
  const int* att_mask     = (const int*)d_in[4];
  const int* rel_ids      = (const int*)d_in[5];
  const float* tok_emb = (const float*)d_in[6];
  const float* seg_emb = (const float*)d_in[7];
  const float* ln1_g = (const float*)d_in[8];
  const float* ln1_b = (const float*)d_in[9];
  const float* ln2_g = (const float*)d_in[10];
  const float* ln2_b = (const float*)d_in[11];
  const float* wq = (const float*)d_in[12];
  const float* bq = (const float*)d_in[13];
  const float* wk = (const float*)d_in[14];
  const float* bk = (const float*)d_in[15];
  const float* wv = (const float*)d_in[16];
  const float* bv = (const float*)d_in[17];
  const float* wo = (const float*)d_in[18];
  const float* bo = (const float*)d_in[19];
  const float* rel_emb = (const float*)d_in[20];
  const float* w1 = (const float*)d_in[21];
  const float* b1 = (const float*)d_in[22];
  const float* w2 = (const float*)d_in[23];
  const float* b2 = (const float*)d_in[24];

  const size_t NTOK = (size_t)B_ * S_ * D_;     // 1,572,864 elems
  const size_t BF = NTOK * 2;                   // bytes per bf16 activation

  float* x = (float*)d_out;                     // residual stream f32 in d_out
  char* ws = (char*)d_ws;
  __hip_bfloat16* h = (__hip_bfloat16*)(ws);
  __hip_bfloat16* q = (__hip_bfloat16*)(ws + BF);
  __hip_bfloat16* k = (__hip_bfloat16*)(ws + 2 * BF);
  __hip_bfloat16* v = (__hip_bfloat16*)(ws + 3 * BF);
  // ffn (B*S*F bf16 = 12.58MB) aliases q,k,v (dead during FFN) + 3.15MB; peak 15.73MB
  __hip_bfloat16* ffn = (__hip_bfloat16*)(ws + BF);

  embed_kernel<<<B_ * S_, 256, 0, stream>>>(token_ids, segment_ids, position_ids,
                                            question_mask, tok_emb, seg_emb, x);

  dim3 gProj(D_ / 128, (B_ * S_) / 128);   // (6, 16)
  dim3 gFfn1(F_ / 128, (B_ * S_) / 128);   // (24, 16)
  dim3 gAttn(S_ / 64, H_, B_);             // (16, 12, 2)

  for (int l = 0; l < L_; ++l) {
    const float* wq_l = wq + (size_t)l * D_ * D_;
    const float* wk_l = wk + (size_t)l * D_ * D_;
    const float* wv_l = wv + (size_t)l * D_ * D_;
    const float* wo_l = wo + (size_t)l * D_ * D_;
    const float* w1_l = w1 + (size_t)l * D_ * F_;
    const float* w2_l = w2 + (size_t)l * F_ * D_;
    const float* re_l = rel_emb + (size_t)l * R_ * H_ * DH_;

    ln_kernel<<<B_ * S_, 256, 0, stream>>>(x, ln1_g + (size_t)l * D_, ln1_b + (size_t)l * D_, h);
    gemm_mfma<<<gProj, 256, 0, stream>>>(h, wq_l, bq + (size_t)l * D_, q, B_ * S_, D_, D_, GF_BF16OUT);
    gemm_mfma<<<gProj, 256, 0, stream>>>(h, wk_l, bk + (size_t)l * D_, k, B_ * S_, D_, D_, GF_BF16OUT);
    gemm_mfma<<<gProj, 256, 0, stream>>>(h, wv_l, bv + (size_t)l * D_, v, B_ * S_, D_, D_, GF_BF16OUT);
    attn_fa<<<gAttn, 256, 0, stream>>>(q, k, v, re_l, rel_ids, att_mask, h);
    gemm_mfma<<<gProj, 256, 0, stream>>>(h, wo_l, bo + (size_t)l * D_, x, B_ * S_, D_, D_, GF_RES);
    ln_kernel<<<B_ * S_, 256, 0, stream>>>(x, ln2_g + (size_t)l * D_, ln2_b + (size_t)l * D_, h);
    gemm_mfma<<<gFfn1, 256, 0, stream>>>(h, w1_l, b1 + (size_t)l * F_, ffn, B_ * S_, F_, D_,
                                         GF_GELU | GF_BF16OUT);
    gemm_mfma<<<gProj, 256, 0, stream>>>(ffn, w2_l, b2 + (size_t)l * D_, x, B_ * S_, D_, F_, GF_RES);
  }
  // x == d_out (f32): done.
}